// Round 5
// baseline (1323.885 us; speedup 1.0000x reference)
//
#include <hip/hip_runtime.h>
#include <hip/hip_bf16.h>

typedef __hip_bfloat16 bf16;
typedef __attribute__((ext_vector_type(8))) short bf16x8;  // 8 bf16 = 4 VGPRs (MFMA A/B frag)
typedef __attribute__((ext_vector_type(4))) short bf16x4;  // 4 bf16 = 8B packed store
typedef __attribute__((ext_vector_type(4))) float f32x4;   // MFMA C/D frag

#define D_MODEL 2048
#define SEQ     2048
#define NH      16
#define DH      128
#define BATCH   2
#define MTOT    (BATCH*SEQ)   // 4096

__device__ __forceinline__ void async_cp16(const bf16* g, bf16* l) {
    // wave-uniform LDS base; HW scatters lane i at base + i*16B
    __builtin_amdgcn_global_load_lds(
        (const __attribute__((address_space(1))) void*)g,
        (__attribute__((address_space(3))) void*)l, 16, 0, 0);
}

__device__ __forceinline__ short bf16bits(float f) {
    bf16 b = __float2bfloat16(f);
    return *reinterpret_cast<short*>(&b);
}

// compiler-level memory fence + raw HW barrier (NOT __syncthreads: that would
// drain vmcnt(0) and kill counted-vmcnt pipelines)
#define GBAR() do { asm volatile("" ::: "memory"); __builtin_amdgcn_s_barrier(); \
                    asm volatile("" ::: "memory"); } while (0)

// ---------------- f32 -> bf16 elementwise convert (8 elems/thread) ----------------
__global__ __launch_bounds__(256) void cvt_k(const float* __restrict__ in,
                                             bf16* __restrict__ out) {
    const long i = ((long)blockIdx.x * 256 + threadIdx.x) * 8;
    float4 a = *(const float4*)(in + i);
    float4 b = *(const float4*)(in + i + 4);
    __align__(16) bf16 t[8];
    t[0] = __float2bfloat16(a.x); t[1] = __float2bfloat16(a.y);
    t[2] = __float2bfloat16(a.z); t[3] = __float2bfloat16(a.w);
    t[4] = __float2bfloat16(b.x); t[5] = __float2bfloat16(b.y);
    t[6] = __float2bfloat16(b.z); t[7] = __float2bfloat16(b.w);
    *(bf16x8*)(out + i) = *(const bf16x8*)t;
}

// ---- f32 [mat][R][Cn] -> bf16 [mat][Cn][R] transpose-convert; 3-src variant for QKV ----
__global__ __launch_bounds__(256) void transpose_cvt3_k(
    const float* __restrict__ in0, const float* __restrict__ in1,
    const float* __restrict__ in2,
    bf16* __restrict__ out, int R, int Cn, int mats_per_src)
{
    __shared__ float t[32][33];
    const int z = blockIdx.z;
    const int src = z / mats_per_src, mat = z % mats_per_src;
    const float* in = (src == 0) ? in0 : (src == 1) ? in1 : in2;
    const float* inm = in + (long)mat * R * Cn;
    bf16* outm = out + (long)z * R * Cn;
    const int c0 = blockIdx.x * 32, r0 = blockIdx.y * 32;
    const int tx = threadIdx.x & 31, ty = threadIdx.x >> 5;   // ty 0..7
#pragma unroll
    for (int i = 0; i < 4; ++i)
        t[ty + i*8][tx] = inm[(long)(r0 + ty + i*8) * Cn + c0 + tx];
    __syncthreads();
#pragma unroll
    for (int i = 0; i < 4; ++i)
        outm[(long)(c0 + ty + i*8) * R + r0 + tx] = __float2bfloat16(t[tx][ty + i*8]);
}

// ---------------- per-head V transpose: [b][key][h*DH+f] -> [(b,h)][f][key] bf16 ----------------
__global__ __launch_bounds__(256) void transpose_v_k(
    const bf16* __restrict__ V, bf16* __restrict__ VT)
{
    __shared__ bf16 t[32][33];
    const int bh = blockIdx.z;              // b*NH + h
    const int b = bh >> 4, h = bh & 15;
    const bf16* inm = V + (long)b*SEQ*D_MODEL + h*DH;       // [key][f] stride D_MODEL
    bf16* outm = VT + (long)bh*DH*SEQ;                      // [f][key] stride SEQ
    const int r0 = blockIdx.x * 32;         // key tile
    const int c0 = blockIdx.y * 32;         // feat tile
    const int tx = threadIdx.x & 31, ty = threadIdx.x >> 5;
#pragma unroll
    for (int i = 0; i < 4; ++i)
        t[ty + i*8][tx] = inm[(long)(r0 + ty + i*8)*D_MODEL + c0 + tx];
    __syncthreads();
#pragma unroll
    for (int i = 0; i < 4; ++i)
        outm[(long)(c0 + ty + i*8)*SEQ + r0 + tx] = t[tx][ty + i*8];
}

// ---------------- 128x128 tile GEMM (kept for out-projection) ----------------
template <bool C_F32>
__device__ __forceinline__ void gemm128x128(
    const bf16* __restrict__ A, int lda,
    const bf16* __restrict__ Bt, int ldb,
    void* __restrict__ C, int ldc,
    const float* __restrict__ bias,
    int Kdim, int m0, int n0)
{
    __shared__ __align__(16) bf16 As[128*32];
    __shared__ __align__(16) bf16 Bs[128*32];
    const int tid  = threadIdx.x;
    const int wave = tid >> 6, lane = tid & 63;
    const int lr = lane & 15, lq = lane >> 4;
    const int wrow = wave >> 1, wcol = wave & 1;
    const int sr = lane >> 2, sk = (lane & 3) * 8;

    const f32x4 zero4 = {0.f, 0.f, 0.f, 0.f};
    f32x4 acc[4][4];
#pragma unroll
    for (int i = 0; i < 4; ++i)
#pragma unroll
        for (int j = 0; j < 4; ++j) acc[i][j] = zero4;

    for (int k0 = 0; k0 < Kdim; k0 += 32) {
#pragma unroll
        for (int c = 0; c < 2; ++c) {
            const int r = wave*32 + c*16;
            async_cp16(A  + (long)(m0 + r + sr)*lda + k0 + sk, As + r*32);
            async_cp16(Bt + (long)(n0 + r + sr)*ldb + k0 + sk, Bs + r*32);
        }
        __syncthreads();
        bf16x8 af[4], bfr[4];
#pragma unroll
        for (int i = 0; i < 4; ++i)
            af[i] = *(const bf16x8*)(As + (wrow*64 + i*16 + lr)*32 + lq*8);
#pragma unroll
        for (int j = 0; j < 4; ++j)
            bfr[j] = *(const bf16x8*)(Bs + (wcol*64 + j*16 + lr)*32 + lq*8);
#pragma unroll
        for (int i = 0; i < 4; ++i)
#pragma unroll
            for (int j = 0; j < 4; ++j)
                acc[i][j] = __builtin_amdgcn_mfma_f32_16x16x32_bf16(af[i], bfr[j], acc[i][j], 0, 0, 0);
        __syncthreads();
    }
#pragma unroll
    for (int j = 0; j < 4; ++j) {
        const int col = n0 + wcol*64 + j*16 + lr;
        const float bv = bias[col];
#pragma unroll
        for (int i = 0; i < 4; ++i) {
            const int row = m0 + wrow*64 + i*16 + lq*4;
#pragma unroll
            for (int r = 0; r < 4; ++r) {
                const float v = acc[i][j][r] + bv;
                if constexpr (C_F32) ((float*)C)[(long)(row + r)*ldc + col] = v;
                else ((bf16*)C)[(long)(row + r)*ldc + col] = __float2bfloat16(v);
            }
        }
    }
}

// ---------------- output projection (f32 out + f32 bias) ----------------
__global__ __launch_bounds__(256) void out_gemm_k(
    const bf16* __restrict__ Z, const bf16* __restrict__ WOT,
    const float* __restrict__ bO, float* __restrict__ Out)
{
    gemm128x128<true>(Z, D_MODEL, WOT, D_MODEL, Out, D_MODEL, bO, D_MODEL,
                      (int)blockIdx.x*128, (int)blockIdx.y*128);
}

// ---------------- QKV projection: 256x256 8-phase GEMM, 2 blocks/CU ----------------
// C[4096, 6144] = X[4096,2048] x WT3[6144,2048]^T, split-stored to Q/K/V.
// 512 thr / 8 waves (2M x 4N); per-wave 128x64 out = acc[8][4].
// R4 lesson: 128KB LDS -> 1 block/CU -> 1.5 dispatch rounds (x0.75) AND no
// cross-block overlap of sync bubbles (active MfmaUtil only ~42%).
// v2: LDS = 64KB (single-slot kh units) -> 2 independent blocks/CU; all 384
// blocks co-resident in one round; block B's MFMA covers block A's stage/vmcnt
// stalls (m97/m114 TLP mechanism). Pipeline is shallow (stage->use = 2 phases,
// vmcnt(0) twice per K-tile at q1/q3 ends, published by those barriers):
//   q0: read kh0 fm0-3 + B-kh0 | stage kh1(t)   | BAR | 16 MFMA | BAR
//   q1: read kh0 fm4-7         |                | BAR | 16 MFMA | vmcnt(0) | BAR
//   q2: read kh1 fm0-3 + B-kh1 | stage kh0(t+1) | BAR | 16 MFMA | BAR
//   q3: read kh1 fm4-7         |                | BAR | 16 MFMA | vmcnt(0) | BAR
// WAR: kh1 unit free after q3-end barrier (staged next q0); kh0 unit free
// after q1-end barrier (staged next q2).
// T2 swizzle (bank-conflict 1.26e7 -> 0, R4-verified): 64B rows, phys slot =
// logical ^ ((row>>1)&3), pre-swizzled GLOBAL src (rule #21) + ds_read addr.
// T1 XCD-bijective swizzle: nwg=384 %8==0; M-fastest decode so each XCD keeps
// 3 B-panels (3MB) L2-hot.
__global__ __launch_bounds__(512, 4) void qkv_gemm256_k(
    const bf16* __restrict__ A, const bf16* __restrict__ Bt,
    const float* __restrict__ bQ, const float* __restrict__ bK, const float* __restrict__ bV,
    bf16* __restrict__ Qo, bf16* __restrict__ Ko, bf16* __restrict__ Vo)
{
    __shared__ __align__(16) bf16 lds[32768];   // 64KB: A units [0,16384), B at +16384
    bf16* As = lds;
    bf16* Bs = lds + 16384;

    // T1: XCD-aware bijective swizzle (384 blocks = 8 XCDs x 48)
    const int lin = blockIdx.x;                 // 0..383
    const int swz = (lin & 7) * 48 + (lin >> 3);
    const int m0 = (swz & 15) * 256;            // M-fastest within an XCD chunk
    const int n0 = (swz >> 4) * 256;

    const int tid = threadIdx.x, wave = tid >> 6, lane = tid & 63;
    const int wm = wave >> 2, wn = wave & 3;
    const int lr = lane & 15, lq = lane >> 4;
    const int sph = (lr >> 1) & 3;              // read-side slot xor (bits 1-2 of row)

    // stage geometry: chunk = 16 rows x 64B; wave stages chunks 2w, 2w+1
    const int s_r  = lane >> 2;                 // row within chunk
    const int s_sl = lane & 3;                  // 16B slot within 64B row

    auto stageA = [&](int t, int kh) {
        const int k = t*64 + kh*32;
        bf16* u = As + (kh << 13);
#pragma unroll
        for (int i = 0; i < 2; ++i) {
            const int c = wave*2 + i;
            const int r = c*16 + s_r;
            async_cp16(A + (long)(m0 + r)*D_MODEL + k + ((s_sl ^ ((r >> 1) & 3)) * 8),
                       u + c*512);
        }
    };
    auto stageB = [&](int t, int kh) {
        const int k = t*64 + kh*32;
        bf16* u = Bs + (kh << 13);
#pragma unroll
        for (int i = 0; i < 2; ++i) {
            const int c = wave*2 + i;
            const int r = c*16 + s_r;
            async_cp16(Bt + (long)(n0 + r)*D_MODEL + k + ((s_sl ^ ((r >> 1) & 3)) * 8),
                       u + c*512);
        }
    };
    auto rdA = [&](int kh, int fm) -> bf16x8 {
        const int r = wm*128 + fm*16 + lr;
        return *(const bf16x8*)(As + (kh << 13) + r*32 + ((lq ^ sph) * 8));
    };
    auto rdB = [&](int kh, int fn) -> bf16x8 {
        const int r = wn*64 + fn*16 + lr;
        return *(const bf16x8*)(Bs + (kh << 13) + r*32 + ((lq ^ sph) * 8));
    };

    const f32x4 zero4 = {0.f, 0.f, 0.f, 0.f};
    f32x4 acc[8][4];
#pragma unroll
    for (int i = 0; i < 8; ++i)
#pragma unroll
        for (int j = 0; j < 4; ++j) acc[i][j] = zero4;

    const int NT = D_MODEL / 64;   // 32

    // prologue: stage kh0(0); drain; publish
    stageA(0, 0); stageB(0, 0);
    asm volatile("s_waitcnt vmcnt(0)" ::: "memory");
    GBAR();

    for (int t = 0; t < NT; ++t) {
        bf16x8 aF[4], bF[4];

        // ---- q0: kh0, fm 0-3 | stage kh1(t) ----
#pragma unroll
        for (int j = 0; j < 4; ++j) aF[j] = rdA(0, j);
#pragma unroll
        for (int j = 0; j < 4; ++j) bF[j] = rdB(0, j);
        stageA(t, 1); stageB(t, 1);
        GBAR();
        __builtin_amdgcn_s_setprio(1);
#pragma unroll
        for (int j = 0; j < 4; ++j)
#pragma unroll
            for (int fn = 0; fn < 4; ++fn)
                acc[j][fn] = __builtin_amdgcn_mfma_f32_16x16x32_bf16(aF[j], bF[fn], acc[j][fn], 0, 0, 0);
        __builtin_amdgcn_s_setprio(0);
        GBAR();

        // ---- q1: kh0, fm 4-7 (B reused) | publish kh1(t) ----
#pragma unroll
        for (int j = 0; j < 4; ++j) aF[j] = rdA(0, 4 + j);
        GBAR();
        __builtin_amdgcn_s_setprio(1);
#pragma unroll
        for (int j = 0; j < 4; ++j)
#pragma unroll
            for (int fn = 0; fn < 4; ++fn)
                acc[4 + j][fn] = __builtin_amdgcn_mfma_f32_16x16x32_bf16(aF[j], bF[fn], acc[4 + j][fn], 0, 0, 0);
        __builtin_amdgcn_s_setprio(0);
        asm volatile("s_waitcnt vmcnt(0)" ::: "memory");
        GBAR();

        // ---- q2: kh1, fm 0-3 | stage kh0(t+1) ----
#pragma unroll
        for (int j = 0; j < 4; ++j) aF[j] = rdA(1, j);
#pragma unroll
        for (int j = 0; j < 4; ++j) bF[j] = rdB(1, j);
        if (t + 1 < NT) { stageA(t + 1, 0); stageB(t + 1, 0); }
        GBAR();
        __builtin_amdgcn_s_setprio(1);
#pragma unroll
        for (int j = 0; j < 4; ++j)
#pragma unroll
            for (int fn = 0; fn < 4; ++fn)
                acc[j][fn] = __builtin_amdgcn_mfma_f32_16x16x32_bf16(aF[j], bF[fn], acc[j][fn], 0, 0, 0);
        __builtin_amdgcn_s_setprio(0);
        GBAR();

        // ---- q3: kh1, fm 4-7 (B reused) | publish kh0(t+1) ----
#pragma unroll
        for (int j = 0; j < 4; ++j) aF[j] = rdA(1, 4 + j);
        GBAR();
        __builtin_amdgcn_s_setprio(1);
#pragma unroll
        for (int j = 0; j < 4; ++j)
#pragma unroll
            for (int fn = 0; fn < 4; ++fn)
                acc[4 + j][fn] = __builtin_amdgcn_mfma_f32_16x16x32_bf16(aF[j], bF[fn], acc[4 + j][fn], 0, 0, 0);
        __builtin_amdgcn_s_setprio(0);
        asm volatile("s_waitcnt vmcnt(0)" ::: "memory");
        GBAR();
    }

    // epilogue: split-store into Q/K/V (sel uniform per block: 256-tile never
    // crosses a 2048 boundary), bias from flat [2048] per-sel vector
    const int gc0 = n0 + wn*64;
    const int sel = gc0 >> 11;
    bf16* C        = (sel == 0) ? Qo : (sel == 1) ? Ko : Vo;
    const float* bs = (sel == 0) ? bQ : (sel == 1) ? bK : bV;
#pragma unroll
    for (int fn = 0; fn < 4; ++fn) {
        const int dcol = (gc0 + fn*16 + lr) & 2047;
        const float bv = bs[dcol];
#pragma unroll
        for (int fm = 0; fm < 8; ++fm) {
            const int row = m0 + wm*128 + fm*16 + lq*4;
#pragma unroll
            for (int rr = 0; rr < 4; ++rr)
                C[(long)(row + rr)*D_MODEL + dcol] = __float2bfloat16(acc[fm][fn][rr] + bv);
        }
    }
}

// ---------------- flash attention: S^T = K Q^T, O^T = V^T P^T ----------------
// QBLK=128, 8 waves (512 thr), KVBLK=64, single-buffered K/V.
// K tile: Ks[key][128feat], 256B rows, 16B-slot XOR swizzle (slot ^= key&7).
// V tile: Vts[feat][64key], 128B rows, 16B-slot XOR swizzle (slot ^= feat&7).
__global__ __launch_bounds__(512) void flash_k(
    const bf16* __restrict__ Q, const bf16* __restrict__ K,
    const bf16* __restrict__ VT, bf16* __restrict__ Z)
{
    __shared__ __align__(16) bf16 Ks[64*128];    // [key][feat] swizzled  16KB
    __shared__ __align__(16) bf16 Vts[128*64];   // [feat][key] swizzled  16KB
    __shared__ __align__(16) bf16 Ps[128*72];    // [qrow][key] pad 72    18KB

    const int qt = (int)(gridDim.x - 1) - (int)blockIdx.x;   // big blocks dispatch first
    const int bh = blockIdx.y;
    const int b  = bh >> 4, h = bh & 15;
    const long base = (long)b*SEQ*D_MODEL + h*DH;
    const bf16* Qb  = Q + base;
    const bf16* Kb  = K + base;
    const bf16* VTb = VT + (long)bh*DH*SEQ;      // [feat][key] stride SEQ
    bf16* Zb = Z + base;
    const int q0 = qt*128;
    const int tid = threadIdx.x, wave = tid >> 6, lane = tid & 63;
    const int lr = lane & 15, lq = lane >> 4;
    const int rx = lr & 7;                        // read-side swizzle key (row&7)

    const int ks_key_off = lane >> 4;             // key within 4-row chunk
    const int ks_slot    = lane & 15;             // 16B slot within 256B row
    const int vt_row_off = lane >> 3;             // feat within 8-row chunk
    const int vt_slot    = lane & 7;              // 16B slot within 128B row

    // Q B-frags in registers: lane holds q-row (q0+wave*16+lr), feats ks*32+lq*8..+8
    bf16x8 aq[4];
#pragma unroll
    for (int ks = 0; ks < 4; ++ks)
        aq[ks] = *(const bf16x8*)(Qb + (long)(q0 + wave*16 + lr)*D_MODEL + ks*32 + lq*8);

    const f32x4 zero4 = {0.f, 0.f, 0.f, 0.f};
    f32x4 o_acc[8];           // O^T: col=qrow(lr), row=feat(jf*16+lq*4+r)
#pragma unroll
    for (int jf = 0; jf < 8; ++jf) o_acc[jf] = zero4;
    float m_run = -1e30f, l_run = 0.f;   // per-lane (qrow=lr), scaled domain

    const float scale = 0.08838834764831845f;  // 1/sqrt(128)
    const int NT = 2*qt + 2;   // key tiles covering rows q0..q0+127

    for (int kt = 0; kt < NT; ++kt) {
        const int k0 = kt*64;
        __syncthreads();   // all waves done reading Ks/Vts of prev tile
#pragma unroll
        for (int c2 = 0; c2 < 2; ++c2) {
            const int c = wave*2 + c2;
            const int key = c*4 + ks_key_off;
            async_cp16(Kb + (long)(k0 + key)*D_MODEL + ((ks_slot ^ (key & 7)) * 8),
                       Ks + c*512);
            const int f = c*8 + vt_row_off;
            async_cp16(VTb + (long)f*SEQ + k0 + ((vt_slot ^ (f & 7)) * 8),
                       Vts + c*512);
        }
        __syncthreads();   // drains vmcnt(0): tile ready

        // fully-masked wave (all 16 q-rows below this key tile)? skip compute
        const int rel_hi = q0 + wave*16 + 15 - k0;
        if (rel_hi >= 0) {
            f32x4 sc[4];
#pragma unroll
            for (int mt = 0; mt < 4; ++mt) sc[mt] = zero4;
            __builtin_amdgcn_s_setprio(1);
#pragma unroll
            for (int mt = 0; mt < 4; ++mt)
#pragma unroll
                for (int ks = 0; ks < 4; ++ks) {
                    bf16x8 bk = *(const bf16x8*)(Ks + (mt*16 + lr)*128 + (((ks*4 + lq) ^ rx) * 8));
                    sc[mt] = __builtin_amdgcn_mfma_f32_16x16x32_bf16(bk, aq[ks], sc[mt], 0, 0, 0);
                }
            __builtin_amdgcn_s_setprio(0);

            if (rel_hi < 78) {
                const int rel = q0 + wave*16 + lr - k0;
#pragma unroll
                for (int mt = 0; mt < 4; ++mt)
#pragma unroll
                    for (int r = 0; r < 4; ++r)
                        if (mt*16 + lq*4 + r > rel) sc[mt][r] = -1e30f;
            }

            float mx = sc[0][0];
#pragma unroll
            for (int mt = 0; mt < 4; ++mt)
#pragma unroll
                for (int r = 0; r < 4; ++r) mx = fmaxf(mx, sc[mt][r]);
            mx = fmaxf(mx, __shfl_xor(mx, 16, 64));
            mx = fmaxf(mx, __shfl_xor(mx, 32, 64));
            mx *= scale;

            if (!__all(mx - m_run <= 8.0f)) {
                const float mn = fmaxf(m_run, mx);
                const float al = __expf(m_run - mn);
                l_run *= al;
#pragma unroll
                for (int jf = 0; jf < 8; ++jf)
#pragma unroll
                    for (int r = 0; r < 4; ++r) o_acc[jf][r] *= al;
                m_run = mn;
            }

            float rs = 0.f;
#pragma unroll
            for (int mt = 0; mt < 4; ++mt)
#pragma unroll
                for (int r = 0; r < 4; ++r) {
                    const float p = __expf(fmaf(sc[mt][r], scale, -m_run));
                    sc[mt][r] = p;
                    rs += p;
                }
            rs += __shfl_xor(rs, 16, 64);
            rs += __shfl_xor(rs, 32, 64);
            l_run += rs;

#pragma unroll
            for (int mt = 0; mt < 4; ++mt) {
                bf16x4 pk;
#pragma unroll
                for (int r = 0; r < 4; ++r) pk[r] = bf16bits(sc[mt][r]);
                *(bf16x4*)(Ps + (wave*16 + lr)*72 + mt*16 + lq*4) = pk;
            }

            bf16x8 pb0 = *(const bf16x8*)(Ps + (wave*16 + lr)*72 + lq*8);
            bf16x8 pb1 = *(const bf16x8*)(Ps + (wave*16 + lr)*72 + 32 + lq*8);

            __builtin_amdgcn_s_setprio(1);
#pragma unroll
            for (int jf = 0; jf < 8; ++jf) {
                const int f = jf*16 + lr;
                bf16x8 av0 = *(const bf16x8*)(Vts + f*64 + ((lq ^ rx) * 8));
                bf16x8 av1 = *(const bf16x8*)(Vts + f*64 + (((4 + lq) ^ rx) * 8));
                o_acc[jf] = __builtin_amdgcn_mfma_f32_16x16x32_bf16(av0, pb0, o_acc[jf], 0, 0, 0);
                o_acc[jf] = __builtin_amdgcn_mfma_f32_16x16x32_bf16(av1, pb1, o_acc[jf], 0, 0, 0);
            }
            __builtin_amdgcn_s_setprio(0);
        }
    }

    const float inv = 1.f / l_run;
    const long zrow = (long)(q0 + wave*16 + lr) * D_MODEL;
#pragma unroll
    for (int jf = 0; jf < 8; ++jf) {
        bf16x4 pk;
#pragma unroll
        for (int r = 0; r < 4; ++r) pk[r] = bf16bits(o_acc[jf][r] * inv);
        *(bf16x4*)(Zb + zrow + jf*16 + lq*4) = pk;
    }
}

extern "C" void kernel_launch(void* const* d_in, const int* in_sizes, int n_in,
                              void* d_out, int out_size, void* d_ws, size_t ws_size,
                              hipStream_t stream) {
    const float* X  = (const float*)d_in[0];
    const float* WQ = (const float*)d_in[1];   // [NH][D_MODEL][DH] f32
    const float* WK = (const float*)d_in[2];
    const float* WV = (const float*)d_in[3];
    const float* WO = (const float*)d_in[4];   // flat [2048][2048] f32
    const float* bQ = (const float*)d_in[5];
    const float* bK = (const float*)d_in[6];
    const float* bV = (const float*)d_in[7];
    const float* bO = (const float*)d_in[8];
    float* out = (float*)d_out;

    bf16* ws = (bf16*)d_ws;
    const long WSZ = (long)NH*DH*D_MODEL;   // 4,194,304 elems (8 MiB bf16)
    const long MSZ = (long)MTOT*D_MODEL;    // 8,388,608 elems (16 MiB bf16)
    bf16* Xb  = ws;
    bf16* WT3 = Xb + MSZ;        // 3*WSZ: transposed QKV weights [48][DH][D_MODEL]
    bf16* WOT = WT3 + 3*WSZ;
    bf16* Qb  = WOT + WSZ;
    bf16* Kb  = Qb + MSZ;
    bf16* Vb  = Kb + MSZ;
    bf16* Zb  = Xb;              // alias: X dead after QKV GEMM
    bf16* VT  = WT3;             // alias: QKV weight transposes dead after QKV GEMM
    // ws use: MSZ + 4*WSZ + 3*MSZ = 96 MiB

    cvt_k<<<MSZ/(256*8), 256, 0, stream>>>(X, Xb);
    transpose_cvt3_k<<<dim3(DH/32, D_MODEL/32, 3*NH), 256, 0, stream>>>(
        WQ, WK, WV, WT3, D_MODEL, DH, NH);
    transpose_cvt3_k<<<dim3(D_MODEL/32, D_MODEL/32, 1), 256, 0, stream>>>(
        WO, WO, WO, WOT, D_MODEL, D_MODEL, 1);

    qkv_gemm256_k<<<dim3((MTOT/256)*(3*D_MODEL/256)), 512, 0, stream>>>(
        Xb, WT3, bQ, bK, bV, Qb, Kb, Vb);
    transpose_v_k<<<dim3(SEQ/32, DH/32, BATCH*NH), 256, 0, stream>>>(Vb, VT);
    flash_k<<<dim3(SEQ/128, BATCH*NH), 512, 0, stream>>>(Qb, Kb, VT, Zb);
    out_gemm_k<<<dim3(MTOT/128, D_MODEL/128), 256, 0, stream>>>(Zb, WOT, bO, out);
}

// Round 6
// 407.984 us; speedup vs baseline: 3.2449x; 3.2449x over previous
//
#include <hip/hip_runtime.h>
#include <hip/hip_bf16.h>

typedef __hip_bfloat16 bf16;
typedef __attribute__((ext_vector_type(8))) short bf16x8;  // 8 bf16 = 4 VGPRs (MFMA A/B frag)
typedef __attribute__((ext_vector_type(4))) short bf16x4;  // 4 bf16 = 8B packed store
typedef __attribute__((ext_vector_type(4))) float f32x4;   // MFMA C/D frag

#define D_MODEL 2048
#define SEQ     2048
#define NH      16
#define DH      128
#define BATCH   2
#define MTOT    (BATCH*SEQ)   // 4096

__device__ __forceinline__ void async_cp16(const bf16* g, bf16* l) {
    // wave-uniform LDS base; HW scatters lane i at base + i*16B
    __builtin_amdgcn_global_load_lds(
        (const __attribute__((address_space(1))) void*)g,
        (__attribute__((address_space(3))) void*)l, 16, 0, 0);
}

__device__ __forceinline__ short bf16bits(float f) {
    bf16 b = __float2bfloat16(f);
    return *reinterpret_cast<short*>(&b);
}

// compiler-level memory fence + raw HW barrier (NOT __syncthreads: that would
// drain vmcnt(0) and kill counted-vmcnt pipelines)
#define GBAR() do { asm volatile("" ::: "memory"); __builtin_amdgcn_s_barrier(); \
                    asm volatile("" ::: "memory"); } while (0)

// ---------------- f32 -> bf16 elementwise convert (8 elems/thread) ----------------
__global__ __launch_bounds__(256) void cvt_k(const float* __restrict__ in,
                                             bf16* __restrict__ out) {
    const long i = ((long)blockIdx.x * 256 + threadIdx.x) * 8;
    float4 a = *(const float4*)(in + i);
    float4 b = *(const float4*)(in + i + 4);
    __align__(16) bf16 t[8];
    t[0] = __float2bfloat16(a.x); t[1] = __float2bfloat16(a.y);
    t[2] = __float2bfloat16(a.z); t[3] = __float2bfloat16(a.w);
    t[4] = __float2bfloat16(b.x); t[5] = __float2bfloat16(b.y);
    t[6] = __float2bfloat16(b.z); t[7] = __float2bfloat16(b.w);
    *(bf16x8*)(out + i) = *(const bf16x8*)t;
}

// ---- f32 [mat][R][Cn] -> bf16 [mat][Cn][R] transpose-convert; 3-src variant for QKV ----
__global__ __launch_bounds__(256) void transpose_cvt3_k(
    const float* __restrict__ in0, const float* __restrict__ in1,
    const float* __restrict__ in2,
    bf16* __restrict__ out, int R, int Cn, int mats_per_src)
{
    __shared__ float t[32][33];
    const int z = blockIdx.z;
    const int src = z / mats_per_src, mat = z % mats_per_src;
    const float* in = (src == 0) ? in0 : (src == 1) ? in1 : in2;
    const float* inm = in + (long)mat * R * Cn;
    bf16* outm = out + (long)z * R * Cn;
    const int c0 = blockIdx.x * 32, r0 = blockIdx.y * 32;
    const int tx = threadIdx.x & 31, ty = threadIdx.x >> 5;   // ty 0..7
#pragma unroll
    for (int i = 0; i < 4; ++i)
        t[ty + i*8][tx] = inm[(long)(r0 + ty + i*8) * Cn + c0 + tx];
    __syncthreads();
#pragma unroll
    for (int i = 0; i < 4; ++i)
        outm[(long)(c0 + ty + i*8) * R + r0 + tx] = __float2bfloat16(t[tx][ty + i*8]);
}

// ---------------- per-head V transpose: [b][key][h*DH+f] -> [(b,h)][f][key] bf16 ----------------
__global__ __launch_bounds__(256) void transpose_v_k(
    const bf16* __restrict__ V, bf16* __restrict__ VT)
{
    __shared__ bf16 t[32][33];
    const int bh = blockIdx.z;              // b*NH + h
    const int b = bh >> 4, h = bh & 15;
    const bf16* inm = V + (long)b*SEQ*D_MODEL + h*DH;       // [key][f] stride D_MODEL
    bf16* outm = VT + (long)bh*DH*SEQ;                      // [f][key] stride SEQ
    const int r0 = blockIdx.x * 32;         // key tile
    const int c0 = blockIdx.y * 32;         // feat tile
    const int tx = threadIdx.x & 31, ty = threadIdx.x >> 5;
#pragma unroll
    for (int i = 0; i < 4; ++i)
        t[ty + i*8][tx] = inm[(long)(r0 + ty + i*8)*D_MODEL + c0 + tx];
    __syncthreads();
#pragma unroll
    for (int i = 0; i < 4; ++i)
        outm[(long)(c0 + ty + i*8)*SEQ + r0 + tx] = t[tx][ty + i*8];
}

// ---------------- 128x128 tile GEMM (kept for out-projection) ----------------
template <bool C_F32>
__device__ __forceinline__ void gemm128x128(
    const bf16* __restrict__ A, int lda,
    const bf16* __restrict__ Bt, int ldb,
    void* __restrict__ C, int ldc,
    const float* __restrict__ bias,
    int Kdim, int m0, int n0)
{
    __shared__ __align__(16) bf16 As[128*32];
    __shared__ __align__(16) bf16 Bs[128*32];
    const int tid  = threadIdx.x;
    const int wave = tid >> 6, lane = tid & 63;
    const int lr = lane & 15, lq = lane >> 4;
    const int wrow = wave >> 1, wcol = wave & 1;
    const int sr = lane >> 2, sk = (lane & 3) * 8;

    const f32x4 zero4 = {0.f, 0.f, 0.f, 0.f};
    f32x4 acc[4][4];
#pragma unroll
    for (int i = 0; i < 4; ++i)
#pragma unroll
        for (int j = 0; j < 4; ++j) acc[i][j] = zero4;

    for (int k0 = 0; k0 < Kdim; k0 += 32) {
#pragma unroll
        for (int c = 0; c < 2; ++c) {
            const int r = wave*32 + c*16;
            async_cp16(A  + (long)(m0 + r + sr)*lda + k0 + sk, As + r*32);
            async_cp16(Bt + (long)(n0 + r + sr)*ldb + k0 + sk, Bs + r*32);
        }
        __syncthreads();
        bf16x8 af[4], bfr[4];
#pragma unroll
        for (int i = 0; i < 4; ++i)
            af[i] = *(const bf16x8*)(As + (wrow*64 + i*16 + lr)*32 + lq*8);
#pragma unroll
        for (int j = 0; j < 4; ++j)
            bfr[j] = *(const bf16x8*)(Bs + (wcol*64 + j*16 + lr)*32 + lq*8);
#pragma unroll
        for (int i = 0; i < 4; ++i)
#pragma unroll
            for (int j = 0; j < 4; ++j)
                acc[i][j] = __builtin_amdgcn_mfma_f32_16x16x32_bf16(af[i], bfr[j], acc[i][j], 0, 0, 0);
        __syncthreads();
    }
#pragma unroll
    for (int j = 0; j < 4; ++j) {
        const int col = n0 + wcol*64 + j*16 + lr;
        const float bv = bias[col];
#pragma unroll
        for (int i = 0; i < 4; ++i) {
            const int row = m0 + wrow*64 + i*16 + lq*4;
#pragma unroll
            for (int r = 0; r < 4; ++r) {
                const float v = acc[i][j][r] + bv;
                if constexpr (C_F32) ((float*)C)[(long)(row + r)*ldc + col] = v;
                else ((bf16*)C)[(long)(row + r)*ldc + col] = __float2bfloat16(v);
            }
        }
    }
}

// ---------------- output projection (f32 out + f32 bias) ----------------
__global__ __launch_bounds__(256) void out_gemm_k(
    const bf16* __restrict__ Z, const bf16* __restrict__ WOT,
    const float* __restrict__ bO, float* __restrict__ Out)
{
    gemm128x128<true>(Z, D_MODEL, WOT, D_MODEL, Out, D_MODEL, bO, D_MODEL,
                      (int)blockIdx.x*128, (int)blockIdx.y*128);
}

// ------- QKV projection: 128x256 tile, BK=32, 3-slot ring, counted vmcnt -------
// C[4096, 6144] = X[4096,2048] x WT3[6144,2048]^T, split-stored to Q/K/V.
// R5 lesson: __launch_bounds__(512,4) caps regs at 128 < acc[8][4]'s 128+ ->
// accumulator spill to scratch (FETCH 1.8GB, 8x slowdown). Fix: shrink the
// TILE, not the reg budget: per-wave out 64x64 -> acc[4][4]=64 regs, total
// ~110-125 naturally <=128 (no forced bound; spill-proof).
// Grid 32x24 = 768 blocks = EXACTLY 3 rounds on 256 CUs (R4's 384-block grid
// was 75% packed). LDS 72KB (3-slot ring: A 3x8KB + B 3x16KB) -> 2 blocks/CU
// if regs <=128; 1 block/CU worst case still packs perfectly.
// T4 counted pipeline: per phase (1 K-step of 32): {8 ds_read frags |
// stage(t+2) 3 loads | setprio 16 MFMA | vmcnt(3) | s_barrier}. Invariant:
// at each phase start exactly 3 loads (tile t+1's) in flight; vmcnt(3) never
// drains to 0 in the main loop (drain only at NT-2/NT-1 tail).
// T2 swizzle (R4-verified, conflicts 1.26e7->0): phys 16B slot = logical ^
// ((row>>1)&3); pre-swizzled GLOBAL src (rule #21) + ds_read addr.
// T1 XCD-bijective: 768 = 8 XCDs x (3 N-panels x 32 M); each XCD's 3 B-panels
// (3MB) stay L2-hot.
__global__ __launch_bounds__(512) void qkv_gemm_k2(
    const bf16* __restrict__ A, const bf16* __restrict__ Bt,
    const float* __restrict__ bQ, const float* __restrict__ bK, const float* __restrict__ bV,
    bf16* __restrict__ Qo, bf16* __restrict__ Ko, bf16* __restrict__ Vo)
{
    __shared__ __align__(16) bf16 lds[36864];   // 72KB: A slots [0,12288), B at +12288
    bf16* As = lds;                              // 3 x [128][32] (4096 elems each)
    bf16* Bs = lds + 12288;                      // 3 x [256][32] (8192 elems each)

    // T1: XCD-aware bijective swizzle (768 blocks = 8 XCDs x 96)
    const int lin = blockIdx.x;                  // 0..767
    const int xcd = lin & 7, idx = lin >> 3;     // idx 0..95
    const int m0 = (idx & 31) * 128;             // M-fastest within an XCD chunk
    const int n0 = (xcd * 3 + (idx >> 5)) * 256; // 3 N-panels per XCD

    const int tid = threadIdx.x, wave = tid >> 6, lane = tid & 63;
    const int wm = wave >> 2, wn = wave & 3;     // 2M x 4N waves
    const int lr = lane & 15, lq = lane >> 4;
    const int sph = (lr >> 1) & 3;               // read-side slot xor (row bits 1-2)

    // stage geometry: chunk = 16 rows x 64B (1KB); A: wave stages chunk w;
    // B: wave stages chunks 2w, 2w+1
    const int s_r  = lane >> 2;                  // row within chunk
    const int s_sl = lane & 3;                   // 16B slot within 64B row

    auto stageA = [&](int t, int slot) {
        const int k = t * 32;
        const int r = wave*16 + s_r;
        async_cp16(A + (long)(m0 + r)*D_MODEL + k + ((s_sl ^ ((r >> 1) & 3)) * 8),
                   As + slot*4096 + wave*512);
    };
    auto stageB = [&](int t, int slot) {
        const int k = t * 32;
#pragma unroll
        for (int i = 0; i < 2; ++i) {
            const int c = wave*2 + i;
            const int r = c*16 + s_r;
            async_cp16(Bt + (long)(n0 + r)*D_MODEL + k + ((s_sl ^ ((r >> 1) & 3)) * 8),
                       Bs + slot*8192 + c*512);
        }
    };
    auto rdA = [&](int slot, int fm) -> bf16x8 {
        const int r = wm*64 + fm*16 + lr;
        return *(const bf16x8*)(As + slot*4096 + r*32 + ((lq ^ sph) * 8));
    };
    auto rdB = [&](int slot, int fn) -> bf16x8 {
        const int r = wn*64 + fn*16 + lr;
        return *(const bf16x8*)(Bs + slot*8192 + r*32 + ((lq ^ sph) * 8));
    };

    const f32x4 zero4 = {0.f, 0.f, 0.f, 0.f};
    f32x4 acc[4][4];
#pragma unroll
    for (int i = 0; i < 4; ++i)
#pragma unroll
        for (int j = 0; j < 4; ++j) acc[i][j] = zero4;

    const int NT = D_MODEL / 32;   // 64

    // prologue: stage t0->slot0, t1->slot1 (6 loads); vmcnt(3) completes t0,
    // keeps t1's 3 in flight; publish.
    stageA(0, 0); stageB(0, 0);
    stageA(1, 1); stageB(1, 1);
    asm volatile("s_waitcnt vmcnt(3)" ::: "memory");
    GBAR();

    int cur = 0, s2 = 2;   // read slot = t%3, stage slot = (t+2)%3
    for (int t = 0; t < NT; ++t) {
        bf16x8 aF[4], bF[4];
#pragma unroll
        for (int j = 0; j < 4; ++j) aF[j] = rdA(cur, j);
#pragma unroll
        for (int j = 0; j < 4; ++j) bF[j] = rdB(cur, j);
        if (t + 2 < NT) { stageA(t + 2, s2); stageB(t + 2, s2); }

        __builtin_amdgcn_s_setprio(1);
#pragma unroll
        for (int fm = 0; fm < 4; ++fm)
#pragma unroll
            for (int fn = 0; fn < 4; ++fn)
                acc[fm][fn] = __builtin_amdgcn_mfma_f32_16x16x32_bf16(aF[fm], bF[fn], acc[fm][fn], 0, 0, 0);
        __builtin_amdgcn_s_setprio(0);

        // counted drain: oldest 3 (tile t+1's loads) must land; keep the 3
        // just issued for t+2 in flight across the barrier (T4)
        if (t + 2 < NT) asm volatile("s_waitcnt vmcnt(3)" ::: "memory");
        else            asm volatile("s_waitcnt vmcnt(0)" ::: "memory");
        GBAR();

        cur = (cur == 2) ? 0 : cur + 1;
        s2  = (s2  == 2) ? 0 : s2  + 1;
    }

    // epilogue: split-store into Q/K/V (sel uniform per block: 256-wide tile
    // never crosses a 2048 boundary), bias from flat [2048] per-sel vector
    const int gc0 = n0 + wn*64;
    const int sel = gc0 >> 11;
    bf16* C        = (sel == 0) ? Qo : (sel == 1) ? Ko : Vo;
    const float* bs = (sel == 0) ? bQ : (sel == 1) ? bK : bV;
#pragma unroll
    for (int fn = 0; fn < 4; ++fn) {
        const int dcol = (gc0 + fn*16 + lr) & 2047;
        const float bv = bs[dcol];
#pragma unroll
        for (int fm = 0; fm < 4; ++fm) {
            const int row = m0 + wm*64 + fm*16 + lq*4;
#pragma unroll
            for (int rr = 0; rr < 4; ++rr)
                C[(long)(row + rr)*D_MODEL + dcol] = __float2bfloat16(acc[fm][fn][rr] + bv);
        }
    }
}

// ---------------- flash attention: S^T = K Q^T, O^T = V^T P^T ----------------
// QBLK=128, 8 waves (512 thr), KVBLK=64, single-buffered K/V.
// K tile: Ks[key][128feat], 256B rows, 16B-slot XOR swizzle (slot ^= key&7).
// V tile: Vts[feat][64key], 128B rows, 16B-slot XOR swizzle (slot ^= feat&7).
__global__ __launch_bounds__(512) void flash_k(
    const bf16* __restrict__ Q, const bf16* __restrict__ K,
    const bf16* __restrict__ VT, bf16* __restrict__ Z)
{
    __shared__ __align__(16) bf16 Ks[64*128];    // [key][feat] swizzled  16KB
    __shared__ __align__(16) bf16 Vts[128*64];   // [feat][key] swizzled  16KB
    __shared__ __align__(16) bf16 Ps[128*72];    // [qrow][key] pad 72    18KB

    const int qt = (int)(gridDim.x - 1) - (int)blockIdx.x;   // big blocks dispatch first
    const int bh = blockIdx.y;
    const int b  = bh >> 4, h = bh & 15;
    const long base = (long)b*SEQ*D_MODEL + h*DH;
    const bf16* Qb  = Q + base;
    const bf16* Kb  = K + base;
    const bf16* VTb = VT + (long)bh*DH*SEQ;      // [feat][key] stride SEQ
    bf16* Zb = Z + base;
    const int q0 = qt*128;
    const int tid = threadIdx.x, wave = tid >> 6, lane = tid & 63;
    const int lr = lane & 15, lq = lane >> 4;
    const int rx = lr & 7;                        // read-side swizzle key (row&7)

    const int ks_key_off = lane >> 4;             // key within 4-row chunk
    const int ks_slot    = lane & 15;             // 16B slot within 256B row
    const int vt_row_off = lane >> 3;             // feat within 8-row chunk
    const int vt_slot    = lane & 7;              // 16B slot within 128B row

    // Q B-frags in registers: lane holds q-row (q0+wave*16+lr), feats ks*32+lq*8..+8
    bf16x8 aq[4];
#pragma unroll
    for (int ks = 0; ks < 4; ++ks)
        aq[ks] = *(const bf16x8*)(Qb + (long)(q0 + wave*16 + lr)*D_MODEL + ks*32 + lq*8);

    const f32x4 zero4 = {0.f, 0.f, 0.f, 0.f};
    f32x4 o_acc[8];           // O^T: col=qrow(lr), row=feat(jf*16+lq*4+r)
#pragma unroll
    for (int jf = 0; jf < 8; ++jf) o_acc[jf] = zero4;
    float m_run = -1e30f, l_run = 0.f;   // per-lane (qrow=lr), scaled domain

    const float scale = 0.08838834764831845f;  // 1/sqrt(128)
    const int NT = 2*qt + 2;   // key tiles covering rows q0..q0+127

    for (int kt = 0; kt < NT; ++kt) {
        const int k0 = kt*64;
        __syncthreads();   // all waves done reading Ks/Vts of prev tile
#pragma unroll
        for (int c2 = 0; c2 < 2; ++c2) {
            const int c = wave*2 + c2;
            const int key = c*4 + ks_key_off;
            async_cp16(Kb + (long)(k0 + key)*D_MODEL + ((ks_slot ^ (key & 7)) * 8),
                       Ks + c*512);
            const int f = c*8 + vt_row_off;
            async_cp16(VTb + (long)f*SEQ + k0 + ((vt_slot ^ (f & 7)) * 8),
                       Vts + c*512);
        }
        __syncthreads();   // drains vmcnt(0): tile ready

        // fully-masked wave (all 16 q-rows below this key tile)? skip compute
        const int rel_hi = q0 + wave*16 + 15 - k0;
        if (rel_hi >= 0) {
            f32x4 sc[4];
#pragma unroll
            for (int mt = 0; mt < 4; ++mt) sc[mt] = zero4;
            __builtin_amdgcn_s_setprio(1);
#pragma unroll
            for (int mt = 0; mt < 4; ++mt)
#pragma unroll
                for (int ks = 0; ks < 4; ++ks) {
                    bf16x8 bk = *(const bf16x8*)(Ks + (mt*16 + lr)*128 + (((ks*4 + lq) ^ rx) * 8));
                    sc[mt] = __builtin_amdgcn_mfma_f32_16x16x32_bf16(bk, aq[ks], sc[mt], 0, 0, 0);
                }
            __builtin_amdgcn_s_setprio(0);

            if (rel_hi < 78) {
                const int rel = q0 + wave*16 + lr - k0;
#pragma unroll
                for (int mt = 0; mt < 4; ++mt)
#pragma unroll
                    for (int r = 0; r < 4; ++r)
                        if (mt*16 + lq*4 + r > rel) sc[mt][r] = -1e30f;
            }

            float mx = sc[0][0];
#pragma unroll
            for (int mt = 0; mt < 4; ++mt)
#pragma unroll
                for (int r = 0; r < 4; ++r) mx = fmaxf(mx, sc[mt][r]);
            mx = fmaxf(mx, __shfl_xor(mx, 16, 64));
            mx = fmaxf(mx, __shfl_xor(mx, 32, 64));
            mx *= scale;

            if (!__all(mx - m_run <= 8.0f)) {
                const float mn = fmaxf(m_run, mx);
                const float al = __expf(m_run - mn);
                l_run *= al;
#pragma unroll
                for (int jf = 0; jf < 8; ++jf)
#pragma unroll
                    for (int r = 0; r < 4; ++r) o_acc[jf][r] *= al;
                m_run = mn;
            }

            float rs = 0.f;
#pragma unroll
            for (int mt = 0; mt < 4; ++mt)
#pragma unroll
                for (int r = 0; r < 4; ++r) {
                    const float p = __expf(fmaf(sc[mt][r], scale, -m_run));
                    sc[mt][r] = p;
                    rs += p;
                }
            rs += __shfl_xor(rs, 16, 64);
            rs += __shfl_xor(rs, 32, 64);
            l_run += rs;

#pragma unroll
            for (int mt = 0; mt < 4; ++mt) {
                bf16x4 pk;
#pragma unroll
                for (int r = 0; r < 4; ++r) pk[r] = bf16bits(sc[mt][r]);
                *(bf16x4*)(Ps + (wave*16 + lr)*72 + mt*16 + lq*4) = pk;
            }

            bf16x8 pb0 = *(const bf16x8*)(Ps + (wave*16 + lr)*72 + lq*8);
            bf16x8 pb1 = *(const bf16x8*)(Ps + (wave*16 + lr)*72 + 32 + lq*8);

            __builtin_amdgcn_s_setprio(1);
#pragma unroll
            for (int jf = 0; jf < 8; ++jf) {
                const int f = jf*16 + lr;
                bf16x8 av0 = *(const bf16x8*)(Vts + f*64 + ((lq ^ rx) * 8));
                bf16x8 av1 = *(const bf16x8*)(Vts + f*64 + (((4 + lq) ^ rx) * 8));
                o_acc[jf] = __builtin_amdgcn_mfma_f32_16x16x32_bf16(av0, pb0, o_acc[jf], 0, 0, 0);
                o_acc[jf] = __builtin_amdgcn_mfma_f32_16x16x32_bf16(av1, pb1, o_acc[jf], 0, 0, 0);
            }
            __builtin_amdgcn_s_setprio(0);
        }
    }

    const float inv = 1.f / l_run;
    const long zrow = (long)(q0 + wave*16 + lr) * D_MODEL;
#pragma unroll
    for (int jf = 0; jf < 8; ++jf) {
        bf16x4 pk;
#pragma unroll
        for (int r = 0; r < 4; ++r) pk[r] = bf16bits(o_acc[jf][r] * inv);
        *(bf16x4*)(Zb + zrow + jf*16 + lq*4) = pk;
    }
}

extern "C" void kernel_launch(void* const* d_in, const int* in_sizes, int n_in,
                              void* d_out, int out_size, void* d_ws, size_t ws_size,
                              hipStream_t stream) {
    const float* X  = (const float*)d_in[0];
    const float* WQ = (const float*)d_in[1];   // [NH][D_MODEL][DH] f32
    const float* WK = (const float*)d_in[2];
    const float* WV = (const float*)d_in[3];
    const float* WO = (const float*)d_in[4];   // flat [2048][2048] f32
    const float* bQ = (const float*)d_in[5];
    const float* bK = (const float*)d_in[6];
    const float* bV = (const float*)d_in[7];
    const float* bO = (const float*)d_in[8];
    float* out = (float*)d_out;

    bf16* ws = (bf16*)d_ws;
    const long WSZ = (long)NH*DH*D_MODEL;   // 4,194,304 elems (8 MiB bf16)
    const long MSZ = (long)MTOT*D_MODEL;    // 8,388,608 elems (16 MiB bf16)
    bf16* Xb  = ws;
    bf16* WT3 = Xb + MSZ;        // 3*WSZ: transposed QKV weights [48][DH][D_MODEL]
    bf16* WOT = WT3 + 3*WSZ;
    bf16* Qb  = WOT + WSZ;
    bf16* Kb  = Qb + MSZ;
    bf16* Vb  = Kb + MSZ;
    bf16* Zb  = Xb;              // alias: X dead after QKV GEMM
    bf16* VT  = WT3;             // alias: QKV weight transposes dead after QKV GEMM
    // ws use: MSZ + 4*WSZ + 3*MSZ = 96 MiB

    cvt_k<<<MSZ/(256*8), 256, 0, stream>>>(X, Xb);
    transpose_cvt3_k<<<dim3(DH/32, D_MODEL/32, 3*NH), 256, 0, stream>>>(
        WQ, WK, WV, WT3, D_MODEL, DH, NH);
    transpose_cvt3_k<<<dim3(D_MODEL/32, D_MODEL/32, 1), 256, 0, stream>>>(
        WO, WO, WO, WOT, D_MODEL, D_MODEL, 1);

    qkv_gemm_k2<<<dim3((MTOT/128)*(3*D_MODEL/256)), 512, 0, stream>>>(
        Xb, WT3, bQ, bK, bV, Qb, Kb, Vb);
    transpose_v_k<<<dim3(SEQ/32, DH/32, BATCH*NH), 256, 0, stream>>>(Vb, VT);
    flash_k<<<dim3(SEQ/128, BATCH*NH), 512, 0, stream>>>(Qb, Kb, VT, Zb);
    out_gemm_k<<<dim3(MTOT/128, D_MODEL/128), 256, 0, stream>>>(Zb, WOT, bO, out);
}

// Round 8
// 396.003 us; speedup vs baseline: 3.3431x; 1.0303x over previous
//
#include <hip/hip_runtime.h>
#include <hip/hip_bf16.h>

typedef __hip_bfloat16 bf16;
typedef __attribute__((ext_vector_type(8))) short bf16x8;  // 8 bf16 = 4 VGPRs (MFMA A/B frag)
typedef __attribute__((ext_vector_type(4))) short bf16x4;  // 4 bf16 = 8B packed store
typedef __attribute__((ext_vector_type(4))) float f32x4;   // MFMA C/D frag

#define D_MODEL 2048
#define SEQ     2048
#define NH      16
#define DH      128
#define BATCH   2
#define MTOT    (BATCH*SEQ)   // 4096

__device__ __forceinline__ void async_cp16(const bf16* g, bf16* l) {
    // wave-uniform LDS base; HW scatters lane i at base + i*16B
    __builtin_amdgcn_global_load_lds(
        (const __attribute__((address_space(1))) void*)g,
        (__attribute__((address_space(3))) void*)l, 16, 0, 0);
}

__device__ __forceinline__ short bf16bits(float f) {
    bf16 b = __float2bfloat16(f);
    return *reinterpret_cast<short*>(&b);
}

// compiler-level memory fence + raw HW barrier (NOT __syncthreads: that would
// drain vmcnt(0) and kill counted-vmcnt pipelines)
#define GBAR() do { asm volatile("" ::: "memory"); __builtin_amdgcn_s_barrier(); \
                    asm volatile("" ::: "memory"); } while (0)

// ---------------- f32 -> bf16 elementwise convert (8 elems/thread) ----------------
__global__ __launch_bounds__(256) void cvt_k(const float* __restrict__ in,
                                             bf16* __restrict__ out) {
    const long i = ((long)blockIdx.x * 256 + threadIdx.x) * 8;
    float4 a = *(const float4*)(in + i);
    float4 b = *(const float4*)(in + i + 4);
    __align__(16) bf16 t[8];
    t[0] = __float2bfloat16(a.x); t[1] = __float2bfloat16(a.y);
    t[2] = __float2bfloat16(a.z); t[3] = __float2bfloat16(a.w);
    t[4] = __float2bfloat16(b.x); t[5] = __float2bfloat16(b.y);
    t[6] = __float2bfloat16(b.z); t[7] = __float2bfloat16(b.w);
    *(bf16x8*)(out + i) = *(const bf16x8*)t;
}

// ---- f32 [mat][R][Cn] -> bf16 [mat][Cn][R] transpose-convert; 3-src variant for QKV ----
__global__ __launch_bounds__(256) void transpose_cvt3_k(
    const float* __restrict__ in0, const float* __restrict__ in1,
    const float* __restrict__ in2,
    bf16* __restrict__ out, int R, int Cn, int mats_per_src)
{
    __shared__ float t[32][33];
    const int z = blockIdx.z;
    const int src = z / mats_per_src, mat = z % mats_per_src;
    const float* in = (src == 0) ? in0 : (src == 1) ? in1 : in2;
    const float* inm = in + (long)mat * R * Cn;
    bf16* outm = out + (long)z * R * Cn;
    const int c0 = blockIdx.x * 32, r0 = blockIdx.y * 32;
    const int tx = threadIdx.x & 31, ty = threadIdx.x >> 5;   // ty 0..7
#pragma unroll
    for (int i = 0; i < 4; ++i)
        t[ty + i*8][tx] = inm[(long)(r0 + ty + i*8) * Cn + c0 + tx];
    __syncthreads();
#pragma unroll
    for (int i = 0; i < 4; ++i)
        outm[(long)(c0 + ty + i*8) * R + r0 + tx] = __float2bfloat16(t[tx][ty + i*8]);
}

// ---------------- per-head V transpose: [b][key][h*DH+f] -> [(b,h)][f][key] bf16 ----------------
__global__ __launch_bounds__(256) void transpose_v_k(
    const bf16* __restrict__ V, bf16* __restrict__ VT)
{
    __shared__ bf16 t[32][33];
    const int bh = blockIdx.z;              // b*NH + h
    const int b = bh >> 4, h = bh & 15;
    const bf16* inm = V + (long)b*SEQ*D_MODEL + h*DH;       // [key][f] stride D_MODEL
    bf16* outm = VT + (long)bh*DH*SEQ;                      // [f][key] stride SEQ
    const int r0 = blockIdx.x * 32;         // key tile
    const int c0 = blockIdx.y * 32;         // feat tile
    const int tx = threadIdx.x & 31, ty = threadIdx.x >> 5;
#pragma unroll
    for (int i = 0; i < 4; ++i)
        t[ty + i*8][tx] = inm[(long)(r0 + ty + i*8)*D_MODEL + c0 + tx];
    __syncthreads();
#pragma unroll
    for (int i = 0; i < 4; ++i)
        outm[(long)(c0 + ty + i*8)*SEQ + r0 + tx] = t[tx][ty + i*8];
}

// ------- 128x256 tile, BK=32, 3-slot ring, counted vmcnt, 2-barrier phases -------
// Shared main-loop structure for qkv_gemm_k2 / out_gemm_k2 (R6 base + m201's
// barrier-bracketed MFMA cluster):
//   phase t: { 8 ds_read frags | stage(t+2) 3 loads | BAR |
//              lgkmcnt(0)+sched_barrier | setprio(1) 16 MFMA setprio(0) |
//              vmcnt(3) | BAR }
// vmcnt(3) invariant: at each phase start exactly tile t+1's 3 loads are in
// flight; never drains to 0 mid-loop (T4). T2 swizzle (conflicts 0,
// R4-verified): phys 16B slot = logical ^ ((row>>1)&3) on pre-swizzled
// GLOBAL src (rule #21) + ds_read addr.

// ---------------- QKV projection ----------------
__global__ __launch_bounds__(512) void qkv_gemm_k2(
    const bf16* __restrict__ A, const bf16* __restrict__ Bt,
    const float* __restrict__ bQ, const float* __restrict__ bK, const float* __restrict__ bV,
    bf16* __restrict__ Qo, bf16* __restrict__ Ko, bf16* __restrict__ Vo)
{
    __shared__ __align__(16) bf16 lds[36864];   // 72KB: A slots [0,12288), B at +12288
    bf16* As = lds;                              // 3 x [128][32]
    bf16* Bs = lds + 12288;                      // 3 x [256][32]

    // T1: XCD-aware bijective swizzle (768 blocks = 8 XCDs x 96)
    const int lin = blockIdx.x;                  // 0..767
    const int xcd = lin & 7, idx = lin >> 3;     // idx 0..95
    const int m0 = (idx & 31) * 128;             // M-fastest within an XCD chunk
    const int n0 = (xcd * 3 + (idx >> 5)) * 256; // 3 N-panels per XCD

    const int tid = threadIdx.x, wave = tid >> 6, lane = tid & 63;
    const int wm = wave >> 2, wn = wave & 3;     // 2M x 4N waves
    const int lr = lane & 15, lq = lane >> 4;
    const int sph = (lr >> 1) & 3;               // read-side slot xor (row bits 1-2)
    const int s_r  = lane >> 2;                  // stage: row within 16-row chunk
    const int s_sl = lane & 3;                   // stage: 16B slot within 64B row

    auto stageA = [&](int t, int slot) {
        const int k = t * 32;
        const int r = wave*16 + s_r;
        async_cp16(A + (long)(m0 + r)*D_MODEL + k + ((s_sl ^ ((r >> 1) & 3)) * 8),
                   As + slot*4096 + wave*512);
    };
    auto stageB = [&](int t, int slot) {
        const int k = t * 32;
#pragma unroll
        for (int i = 0; i < 2; ++i) {
            const int c = wave*2 + i;
            const int r = c*16 + s_r;
            async_cp16(Bt + (long)(n0 + r)*D_MODEL + k + ((s_sl ^ ((r >> 1) & 3)) * 8),
                       Bs + slot*8192 + c*512);
        }
    };
    auto rdA = [&](int slot, int fm) -> bf16x8 {
        const int r = wm*64 + fm*16 + lr;
        return *(const bf16x8*)(As + slot*4096 + r*32 + ((lq ^ sph) * 8));
    };
    auto rdB = [&](int slot, int fn) -> bf16x8 {
        const int r = wn*64 + fn*16 + lr;
        return *(const bf16x8*)(Bs + slot*8192 + r*32 + ((lq ^ sph) * 8));
    };

    const f32x4 zero4 = {0.f, 0.f, 0.f, 0.f};
    f32x4 acc[4][4];
#pragma unroll
    for (int i = 0; i < 4; ++i)
#pragma unroll
        for (int j = 0; j < 4; ++j) acc[i][j] = zero4;

    const int NT = D_MODEL / 32;   // 64

    // prologue: stage t0->slot0, t1->slot1 (6 loads); vmcnt(3) completes t0,
    // keeps t1's 3 in flight; publish.
    stageA(0, 0); stageB(0, 0);
    stageA(1, 1); stageB(1, 1);
    asm volatile("s_waitcnt vmcnt(3)" ::: "memory");
    GBAR();

    int cur = 0, s2 = 2;   // read slot = t%3, stage slot = (t+2)%3
    for (int t = 0; t < NT; ++t) {
        bf16x8 aF[4], bF[4];
#pragma unroll
        for (int j = 0; j < 4; ++j) aF[j] = rdA(cur, j);
#pragma unroll
        for (int j = 0; j < 4; ++j) bF[j] = rdB(cur, j);
        if (t + 2 < NT) { stageA(t + 2, s2); stageB(t + 2, s2); }

        // phase-align waves: MFMA clusters stack while next reads cluster
        GBAR();
        asm volatile("s_waitcnt lgkmcnt(0)" ::: "memory");
        __builtin_amdgcn_sched_barrier(0);

        __builtin_amdgcn_s_setprio(1);
#pragma unroll
        for (int fm = 0; fm < 4; ++fm)
#pragma unroll
            for (int fn = 0; fn < 4; ++fn)
                acc[fm][fn] = __builtin_amdgcn_mfma_f32_16x16x32_bf16(aF[fm], bF[fn], acc[fm][fn], 0, 0, 0);
        __builtin_amdgcn_s_setprio(0);

        // counted drain: tile t+1's 3 loads must land; keep t+2's in flight (T4)
        if (t + 2 < NT) asm volatile("s_waitcnt vmcnt(3)" ::: "memory");
        else            asm volatile("s_waitcnt vmcnt(0)" ::: "memory");
        GBAR();

        cur = (cur == 2) ? 0 : cur + 1;
        s2  = (s2  == 2) ? 0 : s2  + 1;
    }

    // epilogue: split-store into Q/K/V (sel uniform per block), flat biases
    const int gc0 = n0 + wn*64;
    const int sel = gc0 >> 11;
    bf16* C        = (sel == 0) ? Qo : (sel == 1) ? Ko : Vo;
    const float* bs = (sel == 0) ? bQ : (sel == 1) ? bK : bV;
#pragma unroll
    for (int fn = 0; fn < 4; ++fn) {
        const int dcol = (gc0 + fn*16 + lr) & 2047;
        const float bv = bs[dcol];
#pragma unroll
        for (int fm = 0; fm < 4; ++fm) {
            const int row = m0 + wm*64 + fm*16 + lq*4;
#pragma unroll
            for (int rr = 0; rr < 4; ++rr)
                C[(long)(row + rr)*D_MODEL + dcol] = __float2bfloat16(acc[fm][fn][rr] + bv);
        }
    }
}

// ---------------- output projection: same k2 structure, f32 out ----------------
// Grid MUST be (MTOT/128)*(D_MODEL/256) = 256 blocks (R7 bug: launched 32 ->
// rows 512..4095 never written). 256 blocks = exactly one round on 256 CUs;
// each XCD owns one 1MB B-panel (L2-resident).
__global__ __launch_bounds__(512) void out_gemm_k2(
    const bf16* __restrict__ A, const bf16* __restrict__ Bt,
    const float* __restrict__ bO, float* __restrict__ Out)
{
    __shared__ __align__(16) bf16 lds[36864];
    bf16* As = lds;
    bf16* Bs = lds + 12288;

    const int lin = blockIdx.x;                  // 0..255
    const int xcd = lin & 7, idx = lin >> 3;     // idx 0..31
    const int m0 = idx * 128;
    const int n0 = xcd * 256;

    const int tid = threadIdx.x, wave = tid >> 6, lane = tid & 63;
    const int wm = wave >> 2, wn = wave & 3;
    const int lr = lane & 15, lq = lane >> 4;
    const int sph = (lr >> 1) & 3;
    const int s_r  = lane >> 2;
    const int s_sl = lane & 3;

    auto stageA = [&](int t, int slot) {
        const int k = t * 32;
        const int r = wave*16 + s_r;
        async_cp16(A + (long)(m0 + r)*D_MODEL + k + ((s_sl ^ ((r >> 1) & 3)) * 8),
                   As + slot*4096 + wave*512);
    };
    auto stageB = [&](int t, int slot) {
        const int k = t * 32;
#pragma unroll
        for (int i = 0; i < 2; ++i) {
            const int c = wave*2 + i;
            const int r = c*16 + s_r;
            async_cp16(Bt + (long)(n0 + r)*D_MODEL + k + ((s_sl ^ ((r >> 1) & 3)) * 8),
                       Bs + slot*8192 + c*512);
        }
    };
    auto rdA = [&](int slot, int fm) -> bf16x8 {
        const int r = wm*64 + fm*16 + lr;
        return *(const bf16x8*)(As + slot*4096 + r*32 + ((lq ^ sph) * 8));
    };
    auto rdB = [&](int slot, int fn) -> bf16x8 {
        const int r = wn*64 + fn*16 + lr;
        return *(const bf16x8*)(Bs + slot*8192 + r*32 + ((lq ^ sph) * 8));
    };

    const f32x4 zero4 = {0.f, 0.f, 0.f, 0.f};
    f32x4 acc[4][4];
#pragma unroll
    for (int i = 0; i < 4; ++i)
#pragma unroll
        for (int j = 0; j < 4; ++j) acc[i][j] = zero4;

    const int NT = D_MODEL / 32;   // 64

    stageA(0, 0); stageB(0, 0);
    stageA(1, 1); stageB(1, 1);
    asm volatile("s_waitcnt vmcnt(3)" ::: "memory");
    GBAR();

    int cur = 0, s2 = 2;
    for (int t = 0; t < NT; ++t) {
        bf16x8 aF[4], bF[4];
#pragma unroll
        for (int j = 0; j < 4; ++j) aF[j] = rdA(cur, j);
#pragma unroll
        for (int j = 0; j < 4; ++j) bF[j] = rdB(cur, j);
        if (t + 2 < NT) { stageA(t + 2, s2); stageB(t + 2, s2); }

        GBAR();
        asm volatile("s_waitcnt lgkmcnt(0)" ::: "memory");
        __builtin_amdgcn_sched_barrier(0);

        __builtin_amdgcn_s_setprio(1);
#pragma unroll
        for (int fm = 0; fm < 4; ++fm)
#pragma unroll
            for (int fn = 0; fn < 4; ++fn)
                acc[fm][fn] = __builtin_amdgcn_mfma_f32_16x16x32_bf16(aF[fm], bF[fn], acc[fm][fn], 0, 0, 0);
        __builtin_amdgcn_s_setprio(0);

        if (t + 2 < NT) asm volatile("s_waitcnt vmcnt(3)" ::: "memory");
        else            asm volatile("s_waitcnt vmcnt(0)" ::: "memory");
        GBAR();

        cur = (cur == 2) ? 0 : cur + 1;
        s2  = (s2  == 2) ? 0 : s2  + 1;
    }

    const int gc0 = n0 + wn*64;
#pragma unroll
    for (int fn = 0; fn < 4; ++fn) {
        const int col = gc0 + fn*16 + lr;
        const float bv = bO[col];
#pragma unroll
        for (int fm = 0; fm < 4; ++fm) {
            const int row = m0 + wm*64 + fm*16 + lq*4;
#pragma unroll
            for (int rr = 0; rr < 4; ++rr)
                Out[(long)(row + rr)*D_MODEL + col] = acc[fm][fn][rr] + bv;
        }
    }
}

// ---------------- flash attention: S^T = K Q^T, O^T = V^T P^T ----------------
// QBLK=128, 8 waves (512 thr), KVBLK=64, single-buffered K/V (R2 A/B: flash
// is not stage-latency-bound; TLP from 2-3 blocks/CU hides it).
// K tile: Ks[key][128feat], 256B rows, 16B-slot XOR swizzle (slot ^= key&7).
// V tile: Vts[feat][64key], 128B rows, 16B-slot XOR swizzle (slot ^= feat&7).
__global__ __launch_bounds__(512) void flash_k(
    const bf16* __restrict__ Q, const bf16* __restrict__ K,
    const bf16* __restrict__ VT, bf16* __restrict__ Z)
{
    __shared__ __align__(16) bf16 Ks[64*128];    // [key][feat] swizzled  16KB
    __shared__ __align__(16) bf16 Vts[128*64];   // [feat][key] swizzled  16KB
    __shared__ __align__(16) bf16 Ps[128*72];    // [qrow][key] pad 72    18KB

    const int qt = (int)(gridDim.x - 1) - (int)blockIdx.x;   // big blocks dispatch first
    const int bh = blockIdx.y;
    const int b  = bh >> 4, h = bh & 15;
    const long base = (long)b*SEQ*D_MODEL + h*DH;
    const bf16* Qb  = Q + base;
    const bf16* Kb  = K + base;
    const bf16* VTb = VT + (long)bh*DH*SEQ;      // [feat][key] stride SEQ
    bf16* Zb = Z + base;
    const int q0 = qt*128;
    const int tid = threadIdx.x, wave = tid >> 6, lane = tid & 63;
    const int lr = lane & 15, lq = lane >> 4;
    const int rx = lr & 7;                        // read-side swizzle key (row&7)

    const int ks_key_off = lane >> 4;             // key within 4-row chunk
    const int ks_slot    = lane & 15;             // 16B slot within 256B row
    const int vt_row_off = lane >> 3;             // feat within 8-row chunk
    const int vt_slot    = lane & 7;              // 16B slot within 128B row

    // Q B-frags in registers: lane holds q-row (q0+wave*16+lr), feats ks*32+lq*8..+8
    bf16x8 aq[4];
#pragma unroll
    for (int ks = 0; ks < 4; ++ks)
        aq[ks] = *(const bf16x8*)(Qb + (long)(q0 + wave*16 + lr)*D_MODEL + ks*32 + lq*8);

    const f32x4 zero4 = {0.f, 0.f, 0.f, 0.f};
    f32x4 o_acc[8];           // O^T: col=qrow(lr), row=feat(jf*16+lq*4+r)
#pragma unroll
    for (int jf = 0; jf < 8; ++jf) o_acc[jf] = zero4;
    float m_run = -1e30f, l_run = 0.f;   // per-lane (qrow=lr), scaled domain

    const float scale = 0.08838834764831845f;  // 1/sqrt(128)
    const int NT = 2*qt + 2;   // key tiles covering rows q0..q0+127

    for (int kt = 0; kt < NT; ++kt) {
        const int k0 = kt*64;
        __syncthreads();   // all waves done reading Ks/Vts of prev tile
#pragma unroll
        for (int c2 = 0; c2 < 2; ++c2) {
            const int c = wave*2 + c2;
            const int key = c*4 + ks_key_off;
            async_cp16(Kb + (long)(k0 + key)*D_MODEL + ((ks_slot ^ (key & 7)) * 8),
                       Ks + c*512);
            const int f = c*8 + vt_row_off;
            async_cp16(VTb + (long)f*SEQ + k0 + ((vt_slot ^ (f & 7)) * 8),
                       Vts + c*512);
        }
        __syncthreads();   // drains vmcnt(0): tile ready

        // fully-masked wave (all 16 q-rows below this key tile)? skip compute
        const int rel_hi = q0 + wave*16 + 15 - k0;
        if (rel_hi >= 0) {
            f32x4 sc[4];
#pragma unroll
            for (int mt = 0; mt < 4; ++mt) sc[mt] = zero4;
            __builtin_amdgcn_s_setprio(1);
#pragma unroll
            for (int mt = 0; mt < 4; ++mt)
#pragma unroll
                for (int ks = 0; ks < 4; ++ks) {
                    bf16x8 bk = *(const bf16x8*)(Ks + (mt*16 + lr)*128 + (((ks*4 + lq) ^ rx) * 8));
                    sc[mt] = __builtin_amdgcn_mfma_f32_16x16x32_bf16(bk, aq[ks], sc[mt], 0, 0, 0);
                }
            __builtin_amdgcn_s_setprio(0);

            if (rel_hi < 78) {
                const int rel = q0 + wave*16 + lr - k0;
#pragma unroll
                for (int mt = 0; mt < 4; ++mt)
#pragma unroll
                    for (int r = 0; r < 4; ++r)
                        if (mt*16 + lq*4 + r > rel) sc[mt][r] = -1e30f;
            }

            float mx = sc[0][0];
#pragma unroll
            for (int mt = 0; mt < 4; ++mt)
#pragma unroll
                for (int r = 0; r < 4; ++r) mx = fmaxf(mx, sc[mt][r]);
            mx = fmaxf(mx, __shfl_xor(mx, 16, 64));
            mx = fmaxf(mx, __shfl_xor(mx, 32, 64));
            mx *= scale;

            if (!__all(mx - m_run <= 8.0f)) {
                const float mn = fmaxf(m_run, mx);
                const float al = __expf(m_run - mn);
                l_run *= al;
#pragma unroll
                for (int jf = 0; jf < 8; ++jf)
#pragma unroll
                    for (int r = 0; r < 4; ++r) o_acc[jf][r] *= al;
                m_run = mn;
            }

            float rs = 0.f;
#pragma unroll
            for (int mt = 0; mt < 4; ++mt)
#pragma unroll
                for (int r = 0; r < 4; ++r) {
                    const float p = __expf(fmaf(sc[mt][r], scale, -m_run));
                    sc[mt][r] = p;
                    rs += p;
                }
            rs += __shfl_xor(rs, 16, 64);
            rs += __shfl_xor(rs, 32, 64);
            l_run += rs;

#pragma unroll
            for (int mt = 0; mt < 4; ++mt) {
                bf16x4 pk;
#pragma unroll
                for (int r = 0; r < 4; ++r) pk[r] = bf16bits(sc[mt][r]);
                *(bf16x4*)(Ps + (wave*16 + lr)*72 + mt*16 + lq*4) = pk;
            }

            bf16x8 pb0 = *(const bf16x8*)(Ps + (wave*16 + lr)*72 + lq*8);
            bf16x8 pb1 = *(const bf16x8*)(Ps + (wave*16 + lr)*72 + 32 + lq*8);

            __builtin_amdgcn_s_setprio(1);
#pragma unroll
            for (int jf = 0; jf < 8; ++jf) {
                const int f = jf*16 + lr;
                bf16x8 av0 = *(const bf16x8*)(Vts + f*64 + ((lq ^ rx) * 8));
                bf16x8 av1 = *(const bf16x8*)(Vts + f*64 + (((4 + lq) ^ rx) * 8));
                o_acc[jf] = __builtin_amdgcn_mfma_f32_16x16x32_bf16(av0, pb0, o_acc[jf], 0, 0, 0);
                o_acc[jf] = __builtin_amdgcn_mfma_f32_16x16x32_bf16(av1, pb1, o_acc[jf], 0, 0, 0);
            }
            __builtin_amdgcn_s_setprio(0);
        }
    }

    const float inv = 1.f / l_run;
    const long zrow = (long)(q0 + wave*16 + lr) * D_MODEL;
#pragma unroll
    for (int jf = 0; jf < 8; ++jf) {
        bf16x4 pk;
#pragma unroll
        for (int r = 0; r < 4; ++r) pk[r] = bf16bits(o_acc[jf][r] * inv);
        *(bf16x4*)(Zb + zrow + jf*16 + lq*4) = pk;
    }
}

extern "C" void kernel_launch(void* const* d_in, const int* in_sizes, int n_in,
                              void* d_out, int out_size, void* d_ws, size_t ws_size,
                              hipStream_t stream) {
    const float* X  = (const float*)d_in[0];
    const float* WQ = (const float*)d_in[1];   // [NH][D_MODEL][DH] f32
    const float* WK = (const float*)d_in[2];
    const float* WV = (const float*)d_in[3];
    const float* WO = (const float*)d_in[4];   // flat [2048][2048] f32
    const float* bQ = (const float*)d_in[5];
    const float* bK = (const float*)d_in[6];
    const float* bV = (const float*)d_in[7];
    const float* bO = (const float*)d_in[8];
    float* out = (float*)d_out;

    bf16* ws = (bf16*)d_ws;
    const long WSZ = (long)NH*DH*D_MODEL;   // 4,194,304 elems (8 MiB bf16)
    const long MSZ = (long)MTOT*D_MODEL;    // 8,388,608 elems (16 MiB bf16)
    bf16* Xb  = ws;
    bf16* WT3 = Xb + MSZ;        // 3*WSZ: transposed QKV weights [48][DH][D_MODEL]
    bf16* WOT = WT3 + 3*WSZ;
    bf16* Qb  = WOT + WSZ;
    bf16* Kb  = Qb + MSZ;
    bf16* Vb  = Kb + MSZ;
    bf16* Zb  = Xb;              // alias: X dead after QKV GEMM
    bf16* VT  = WT3;             // alias: QKV weight transposes dead after QKV GEMM
    // ws use: MSZ + 4*WSZ + 3*MSZ = 96 MiB

    cvt_k<<<MSZ/(256*8), 256, 0, stream>>>(X, Xb);
    transpose_cvt3_k<<<dim3(DH/32, D_MODEL/32, 3*NH), 256, 0, stream>>>(
        WQ, WK, WV, WT3, D_MODEL, DH, NH);
    transpose_cvt3_k<<<dim3(D_MODEL/32, D_MODEL/32, 1), 256, 0, stream>>>(
        WO, WO, WO, WOT, D_MODEL, D_MODEL, 1);

    qkv_gemm_k2<<<dim3((MTOT/128)*(3*D_MODEL/256)), 512, 0, stream>>>(
        Xb, WT3, bQ, bK, bV, Qb, Kb, Vb);
    transpose_v_k<<<dim3(SEQ/32, DH/32, BATCH*NH), 256, 0, stream>>>(Vb, VT);
    flash_k<<<dim3(SEQ/128, BATCH*NH), 512, 0, stream>>>(Qb, Kb, VT, Zb);
    out_gemm_k2<<<dim3((MTOT/128)*(D_MODEL/256)), 512, 0, stream>>>(Zb, WOT, bO, out);
}